// Round 3
// baseline (780.184 us; speedup 1.0000x reference)
//
#include <hip/hip_runtime.h>

__device__ __forceinline__ float lrelu(float v) { return v >= 0.f ? v : 0.2f * v; }

// ---------------- prep: A_l[k][h] = sum_f W[k][h*64+f]*al[h][f] ------------
__global__ __launch_bounds__(256) void k_prep(
    const float* __restrict__ W, const float* __restrict__ al,
    const float* __restrict__ ar, float* __restrict__ Al, float* __restrict__ Ar)
{
    int t = threadIdx.x;
    int k = t >> 2, h = t & 3;
    float sl = 0.f, sr = 0.f;
#pragma unroll 8
    for (int f = 0; f < 64; ++f) {
        float wv = W[k * 256 + h * 64 + f];
        sl = fmaf(wv, al[h * 64 + f], sl);
        sr = fmaf(wv, ar[h * 64 + f], sr);
    }
    Al[k * 4 + h] = sl;
    Ar[k * 4 + h] = sr;
}

// ---------------- el/er = X @ [Al|Ar] : wave per node ----------------------
__global__ __launch_bounds__(256) void k_elr(
    const float* __restrict__ X, const float* __restrict__ Al,
    const float* __restrict__ Ar, float* __restrict__ el, float* __restrict__ er,
    int nNodes)
{
    int lane = threadIdx.x & 63, wid = threadIdx.x >> 6;
    int n = blockIdx.x * 4 + wid;
    if (n >= nNodes) return;
    float xv = X[(size_t)n * 64 + lane];
    float4 a = *reinterpret_cast<const float4*>(Al + lane * 4);
    float4 r = *reinterpret_cast<const float4*>(Ar + lane * 4);
    float p0 = xv * a.x, p1 = xv * a.y, p2 = xv * a.z, p3 = xv * a.w;
    float q0 = xv * r.x, q1 = xv * r.y, q2 = xv * r.z, q3 = xv * r.w;
#pragma unroll
    for (int m = 1; m < 64; m <<= 1) {
        p0 += __shfl_xor(p0, m, 64); p1 += __shfl_xor(p1, m, 64);
        p2 += __shfl_xor(p2, m, 64); p3 += __shfl_xor(p3, m, 64);
        q0 += __shfl_xor(q0, m, 64); q1 += __shfl_xor(q1, m, 64);
        q2 += __shfl_xor(q2, m, 64); q3 += __shfl_xor(q3, m, 64);
    }
    if (lane == 0) {
        *reinterpret_cast<float4*>(el + (size_t)n * 4) = make_float4(p0, p1, p2, p3);
        *reinterpret_cast<float4*>(er + (size_t)n * 4) = make_float4(q0, q1, q2, q3);
    }
}

// ---------------- CSR build -------------------
__global__ void k_hist(const int* __restrict__ dst, int* __restrict__ cnt, int E_) {
    int i = blockIdx.x * blockDim.x + threadIdx.x;
    if (i < E_) atomicAdd(&cnt[dst[i]], 1);
}

#define SC_VPT 8
#define SC_CHUNK 2048  // 256 threads * 8

__global__ __launch_bounds__(256) void k_chunk_sums(const int* __restrict__ cnt,
                                                    int* __restrict__ bsums, int n) {
    int tid = threadIdx.x;
    int base = blockIdx.x * SC_CHUNK + tid * SC_VPT;
    int s = 0;
#pragma unroll
    for (int i = 0; i < SC_VPT; ++i) { int idx = base + i; if (idx < n) s += cnt[idx]; }
    int lane = tid & 63, wid = tid >> 6;
#pragma unroll
    for (int m = 1; m < 64; m <<= 1) s += __shfl_xor(s, m, 64);
    __shared__ int sh[4];
    if (lane == 0) sh[wid] = s;
    __syncthreads();
    if (tid == 0) bsums[blockIdx.x] = sh[0] + sh[1] + sh[2] + sh[3];
}

__global__ void k_scan_mid(int* bsums, int nb) {
    if (threadIdx.x == 0 && blockIdx.x == 0) {
        int acc = 0;
        for (int i = 0; i < nb; ++i) { int v = bsums[i]; bsums[i] = acc; acc += v; }
    }
}

__global__ __launch_bounds__(256) void k_scan_write(const int* __restrict__ cnt,
                                                    const int* __restrict__ bsums,
                                                    int* __restrict__ offs, int n) {
    int tid = threadIdx.x;
    int base = blockIdx.x * SC_CHUNK + tid * SC_VPT;
    int v[SC_VPT]; int s = 0;
#pragma unroll
    for (int i = 0; i < SC_VPT; ++i) { int idx = base + i; v[i] = (idx < n) ? cnt[idx] : 0; s += v[i]; }
    int lane = tid & 63, wid = tid >> 6;
    int sc = s;
#pragma unroll
    for (int d = 1; d < 64; d <<= 1) { int t = __shfl_up(sc, d, 64); if (lane >= d) sc += t; }
    __shared__ int wsum[4];
    if (lane == 63) wsum[wid] = sc;
    __syncthreads();
    int wbase = 0;
    for (int i = 0; i < wid; ++i) wbase += wsum[i];
    int p = bsums[blockIdx.x] + wbase + (sc - s);
#pragma unroll
    for (int i = 0; i < SC_VPT; ++i) {
        int idx = base + i;
        if (idx < n) {
            offs[idx] = p; p += v[i];
            if (idx == n - 1) offs[n] = p;
        }
    }
}

__global__ void k_scatter(const int* __restrict__ src, const int* __restrict__ dst,
                          const int* __restrict__ offs, int* __restrict__ fill,
                          int* __restrict__ esrc, int E_) {
    int i = blockIdx.x * blockDim.x + threadIdx.x;
    if (i < E_) {
        int d = dst[i];
        int pos = offs[d] + atomicAdd(&fill[d], 1);
        esrc[pos] = src[i];
    }
}

// ---------------- per-node edge softmax: per-edge weights [E,4] ------------
__global__ __launch_bounds__(256) void k_stats(
    const int* __restrict__ esrc, const int* __restrict__ offs,
    const float* __restrict__ el, const float* __restrict__ er,
    float* __restrict__ w, int nNodes)
{
    int lane = threadIdx.x & 63, wid = threadIdx.x >> 6;
    int n = blockIdx.x * 4 + wid;
    if (n >= nNodes) return;
    int s0 = offs[n], s1 = offs[n + 1];
    if (s0 == s1) return;
    float4 erv = *reinterpret_cast<const float4*>(er + (size_t)n * 4);

    int j0 = s0 + lane;
    float e0 = -1e30f, e1 = -1e30f, e2 = -1e30f, e3 = -1e30f;
    if (j0 < s1) {
        int s = esrc[j0];
        float4 v = *reinterpret_cast<const float4*>(el + (size_t)s * 4);
        e0 = lrelu(v.x + erv.x); e1 = lrelu(v.y + erv.y);
        e2 = lrelu(v.z + erv.z); e3 = lrelu(v.w + erv.w);
    }
    float m0 = e0, m1 = e1, m2 = e2, m3 = e3;
    for (int j = j0 + 64; j < s1; j += 64) {
        int s = esrc[j];
        float4 v = *reinterpret_cast<const float4*>(el + (size_t)s * 4);
        m0 = fmaxf(m0, lrelu(v.x + erv.x)); m1 = fmaxf(m1, lrelu(v.y + erv.y));
        m2 = fmaxf(m2, lrelu(v.z + erv.z)); m3 = fmaxf(m3, lrelu(v.w + erv.w));
    }
#pragma unroll
    for (int m = 1; m < 64; m <<= 1) {
        m0 = fmaxf(m0, __shfl_xor(m0, m, 64));
        m1 = fmaxf(m1, __shfl_xor(m1, m, 64));
        m2 = fmaxf(m2, __shfl_xor(m2, m, 64));
        m3 = fmaxf(m3, __shfl_xor(m3, m, 64));
    }
    float x0 = expf(e0 - m0), x1 = expf(e1 - m1), x2 = expf(e2 - m2), x3 = expf(e3 - m3);
    float t0 = x0, t1 = x1, t2 = x2, t3 = x3;
    for (int j = j0 + 64; j < s1; j += 64) {
        int s = esrc[j];
        float4 v = *reinterpret_cast<const float4*>(el + (size_t)s * 4);
        t0 += expf(lrelu(v.x + erv.x) - m0); t1 += expf(lrelu(v.y + erv.y) - m1);
        t2 += expf(lrelu(v.z + erv.z) - m2); t3 += expf(lrelu(v.w + erv.w) - m3);
    }
#pragma unroll
    for (int m = 1; m < 64; m <<= 1) {
        t0 += __shfl_xor(t0, m, 64); t1 += __shfl_xor(t1, m, 64);
        t2 += __shfl_xor(t2, m, 64); t3 += __shfl_xor(t3, m, 64);
    }
    float i0 = 1.f / t0, i1 = 1.f / t1, i2 = 1.f / t2, i3 = 1.f / t3;
    if (j0 < s1)
        *reinterpret_cast<float4*>(w + (size_t)j0 * 4) =
            make_float4(x0 * i0, x1 * i1, x2 * i2, x3 * i3);
    for (int j = j0 + 64; j < s1; j += 64) {
        int s = esrc[j];
        float4 v = *reinterpret_cast<const float4*>(el + (size_t)s * 4);
        *reinterpret_cast<float4*>(w + (size_t)j * 4) = make_float4(
            expf(lrelu(v.x + erv.x) - m0) * i0, expf(lrelu(v.y + erv.y) - m1) * i1,
            expf(lrelu(v.z + erv.z) - m2) * i2, expf(lrelu(v.w + erv.w) - m3) * i3);
    }
}

// ---------------- fused gather + projection --------------------------------
// Block = 4 waves. Per group of 4 nodes: wave i gathers node i's
// agg[h][k] (lane=k, 4 head accs) -> LDS; then all 256 threads project
// (thread t owns W column t, reads LDS agg via wave-uniform broadcast),
// fused bias + optional tanh + head-mean.
__global__ __launch_bounds__(256) void k_gp(
    const int* __restrict__ esrc, const int* __restrict__ offs,
    const float* __restrict__ w, const float* __restrict__ X,
    const float* __restrict__ W, const float* __restrict__ B,
    float* __restrict__ out, int nNodes, int groupsPerBlock, int do_tanh)
{
    int tid = threadIdx.x;
    int lane = tid & 63, wid = tid >> 6;
    int hb = __builtin_amdgcn_readfirstlane(tid >> 6);
    float wcol[64];
#pragma unroll
    for (int k = 0; k < 64; ++k) wcol[k] = W[k * 256 + tid];
    float bv = B[tid];

    __shared__ float sh[4][256];

    for (int g = 0; g < groupsPerBlock; ++g) {
        int nbase = (blockIdx.x * groupsPerBlock + g) * 4;
        if (nbase >= nNodes) return;
        int n = nbase + wid;

        // ---- gather phase: this wave owns node n ----
        float a0 = 0.f, a1 = 0.f, a2 = 0.f, a3 = 0.f;
        if (n < nNodes) {
            int s0 = offs[n], s1 = offs[n + 1];
#pragma unroll 2
            for (int j = s0; j < s1; ++j) {
                int s = esrc[j];
                float4 wv = *reinterpret_cast<const float4*>(w + (size_t)j * 4);
                float xv = X[(size_t)s * 64 + lane];
                a0 = fmaf(xv, wv.x, a0); a1 = fmaf(xv, wv.y, a1);
                a2 = fmaf(xv, wv.z, a2); a3 = fmaf(xv, wv.w, a3);
            }
        }
        sh[wid][lane]       = a0;
        sh[wid][64 + lane]  = a1;
        sh[wid][128 + lane] = a2;
        sh[wid][192 + lane] = a3;
        __syncthreads();

        // ---- projection phase: all threads, per node i in group ----
        float vout[4];
#pragma unroll
        for (int i = 0; i < 4; ++i) {
            const float* ar = &sh[i][hb * 64];
            float c0 = 0.f, c1 = 0.f, c2 = 0.f, c3 = 0.f;
#pragma unroll
            for (int k = 0; k < 64; k += 4) {
                c0 = fmaf(ar[k + 0], wcol[k + 0], c0);
                c1 = fmaf(ar[k + 1], wcol[k + 1], c1);
                c2 = fmaf(ar[k + 2], wcol[k + 2], c2);
                c3 = fmaf(ar[k + 3], wcol[k + 3], c3);
            }
            float v = (c0 + c1) + (c2 + c3) + bv;
            if (do_tanh) v = tanhf(v);
            vout[i] = v;
        }
        __syncthreads();
#pragma unroll
        for (int i = 0; i < 4; ++i) sh[i][tid] = vout[i];
        __syncthreads();

        // ---- head-mean + store: thread t -> (node i = t>>6, f = t&63) ----
        int ni = nbase + wid;
        if (ni < nNodes)
            out[(size_t)ni * 64 + lane] =
                0.25f * (sh[wid][lane] + sh[wid][64 + lane] +
                         sh[wid][128 + lane] + sh[wid][192 + lane]);
        __syncthreads();
    }
}

// ---------------- launch -------------------
extern "C" void kernel_launch(void* const* d_in, const int* in_sizes, int n_in,
                              void* d_out, int out_size, void* d_ws, size_t ws_size,
                              hipStream_t stream) {
    const float* x   = (const float*)d_in[0];
    const int*   src = (const int*)d_in[1];
    const int*   dst = (const int*)d_in[2];
    const float* W1  = (const float*)d_in[3];
    const float* al1 = (const float*)d_in[4];
    const float* ar1 = (const float*)d_in[5];
    const float* b1  = (const float*)d_in[6];
    const float* W2  = (const float*)d_in[7];
    const float* al2 = (const float*)d_in[8];
    const float* ar2 = (const float*)d_in[9];
    const float* b2  = (const float*)d_in[10];
    float* out = (float*)d_out;

    int N_ = in_sizes[0] / 64;
    int E_ = in_sizes[1];

    char* ws = (char*)d_ws;
    size_t off = 0;
    auto alloc = [&](size_t bytes) -> void* {
        void* p = ws + off;
        off = (off + bytes + 255) & ~(size_t)255;
        return p;
    };
    float* el   = (float*)alloc((size_t)N_ * 4 * 4);
    float* er   = (float*)alloc((size_t)N_ * 4 * 4);
    float* h1   = (float*)alloc((size_t)N_ * 64 * 4);
    float* w    = (float*)alloc((size_t)E_ * 4 * 4);
    int*   cnt  = (int*)alloc((size_t)N_ * 4);
    int*   offs = (int*)alloc((size_t)(N_ + 1) * 4);
    int*   fill = (int*)alloc((size_t)N_ * 4);
    int*   esrc = (int*)alloc((size_t)E_ * 4);
    int*   bsums= (int*)alloc(4096);
    float* A1l  = (float*)alloc(64 * 4 * 4);
    float* A1r  = (float*)alloc(64 * 4 * 4);
    float* A2l  = (float*)alloc(64 * 4 * 4);
    float* A2r  = (float*)alloc(64 * 4 * 4);

    hipMemsetAsync(cnt, 0, (size_t)N_ * 4, stream);
    hipMemsetAsync(fill, 0, (size_t)N_ * 4, stream);

    k_prep<<<1, 256, 0, stream>>>(W1, al1, ar1, A1l, A1r);
    k_prep<<<1, 256, 0, stream>>>(W2, al2, ar2, A2l, A2r);

    int eb = (E_ + 255) / 256;
    k_hist<<<eb, 256, 0, stream>>>(dst, cnt, E_);
    int nchunks = (N_ + SC_CHUNK - 1) / SC_CHUNK;
    k_chunk_sums<<<nchunks, 256, 0, stream>>>(cnt, bsums, N_);
    k_scan_mid<<<1, 64, 0, stream>>>(bsums, nchunks);
    k_scan_write<<<nchunks, 256, 0, stream>>>(cnt, bsums, offs, N_);
    k_scatter<<<eb, 256, 0, stream>>>(src, dst, offs, fill, esrc, E_);

    int nb4 = (N_ + 3) / 4;
    int gpb = 8;  // groups of 4 nodes per block
    int ggrid = (N_ + 4 * gpb - 1) / (4 * gpb);
    // layer 1
    k_elr<<<nb4, 256, 0, stream>>>(x, A1l, A1r, el, er, N_);
    k_stats<<<nb4, 256, 0, stream>>>(esrc, offs, el, er, w, N_);
    k_gp<<<ggrid, 256, 0, stream>>>(esrc, offs, w, x, W1, b1, h1, N_, gpb, 1);
    // layer 2
    k_elr<<<nb4, 256, 0, stream>>>(h1, A2l, A2r, el, er, N_);
    k_stats<<<nb4, 256, 0, stream>>>(esrc, offs, el, er, w, N_);
    k_gp<<<ggrid, 256, 0, stream>>>(esrc, offs, w, h1, W2, b2, out, N_, gpb, 0);
}

// Round 4
// 676.423 us; speedup vs baseline: 1.1534x; 1.1534x over previous
//
#include <hip/hip_runtime.h>

__device__ __forceinline__ float lrelu(float v) { return v >= 0.f ? v : 0.2f * v; }

// ---------------- prep: A_l[k][h] = sum_f W[k][h*64+f]*al[h][f] ------------
__global__ __launch_bounds__(256) void k_prep(
    const float* __restrict__ W, const float* __restrict__ al,
    const float* __restrict__ ar, float* __restrict__ Al, float* __restrict__ Ar)
{
    int t = threadIdx.x;
    int k = t >> 2, h = t & 3;
    float sl = 0.f, sr = 0.f;
#pragma unroll 8
    for (int f = 0; f < 64; ++f) {
        float wv = W[k * 256 + h * 64 + f];
        sl = fmaf(wv, al[h * 64 + f], sl);
        sr = fmaf(wv, ar[h * 64 + f], sr);
    }
    Al[k * 4 + h] = sl;
    Ar[k * 4 + h] = sr;
}

// ---------------- el/er = X @ [Al|Ar] : wave per node (layer 1 only) -------
__global__ __launch_bounds__(256) void k_elr(
    const float* __restrict__ X, const float* __restrict__ Al,
    const float* __restrict__ Ar, float* __restrict__ el, float* __restrict__ er,
    int nNodes)
{
    int lane = threadIdx.x & 63, wid = threadIdx.x >> 6;
    int n = blockIdx.x * 4 + wid;
    if (n >= nNodes) return;
    float xv = X[(size_t)n * 64 + lane];
    float4 a = *reinterpret_cast<const float4*>(Al + lane * 4);
    float4 r = *reinterpret_cast<const float4*>(Ar + lane * 4);
    float p0 = xv * a.x, p1 = xv * a.y, p2 = xv * a.z, p3 = xv * a.w;
    float q0 = xv * r.x, q1 = xv * r.y, q2 = xv * r.z, q3 = xv * r.w;
#pragma unroll
    for (int m = 1; m < 64; m <<= 1) {
        p0 += __shfl_xor(p0, m, 64); p1 += __shfl_xor(p1, m, 64);
        p2 += __shfl_xor(p2, m, 64); p3 += __shfl_xor(p3, m, 64);
        q0 += __shfl_xor(q0, m, 64); q1 += __shfl_xor(q1, m, 64);
        q2 += __shfl_xor(q2, m, 64); q3 += __shfl_xor(q3, m, 64);
    }
    if (lane == 0) {
        *reinterpret_cast<float4*>(el + (size_t)n * 4) = make_float4(p0, p1, p2, p3);
        *reinterpret_cast<float4*>(er + (size_t)n * 4) = make_float4(q0, q1, q2, q3);
    }
}

// ---------------- CSR build -------------------
__global__ void k_hist(const int* __restrict__ dst, int* __restrict__ cnt, int E_) {
    int i = blockIdx.x * blockDim.x + threadIdx.x;
    if (i < E_) atomicAdd(&cnt[dst[i]], 1);
}

#define SC_VPT 8
#define SC_CHUNK 2048  // 256 threads * 8

__global__ __launch_bounds__(256) void k_chunk_sums(const int* __restrict__ cnt,
                                                    int* __restrict__ bsums, int n) {
    int tid = threadIdx.x;
    int base = blockIdx.x * SC_CHUNK + tid * SC_VPT;
    int s = 0;
#pragma unroll
    for (int i = 0; i < SC_VPT; ++i) { int idx = base + i; if (idx < n) s += cnt[idx]; }
    int lane = tid & 63, wid = tid >> 6;
#pragma unroll
    for (int m = 1; m < 64; m <<= 1) s += __shfl_xor(s, m, 64);
    __shared__ int sh[4];
    if (lane == 0) sh[wid] = s;
    __syncthreads();
    if (tid == 0) bsums[blockIdx.x] = sh[0] + sh[1] + sh[2] + sh[3];
}

__global__ void k_scan_mid(int* bsums, int nb) {
    if (threadIdx.x == 0 && blockIdx.x == 0) {
        int acc = 0;
        for (int i = 0; i < nb; ++i) { int v = bsums[i]; bsums[i] = acc; acc += v; }
    }
}

__global__ __launch_bounds__(256) void k_scan_write(const int* __restrict__ cnt,
                                                    const int* __restrict__ bsums,
                                                    int* __restrict__ offs, int n) {
    int tid = threadIdx.x;
    int base = blockIdx.x * SC_CHUNK + tid * SC_VPT;
    int v[SC_VPT]; int s = 0;
#pragma unroll
    for (int i = 0; i < SC_VPT; ++i) { int idx = base + i; v[i] = (idx < n) ? cnt[idx] : 0; s += v[i]; }
    int lane = tid & 63, wid = tid >> 6;
    int sc = s;
#pragma unroll
    for (int d = 1; d < 64; d <<= 1) { int t = __shfl_up(sc, d, 64); if (lane >= d) sc += t; }
    __shared__ int wsum[4];
    if (lane == 63) wsum[wid] = sc;
    __syncthreads();
    int wbase = 0;
    for (int i = 0; i < wid; ++i) wbase += wsum[i];
    int p = bsums[blockIdx.x] + wbase + (sc - s);
#pragma unroll
    for (int i = 0; i < SC_VPT; ++i) {
        int idx = base + i;
        if (idx < n) {
            offs[idx] = p; p += v[i];
            if (idx == n - 1) offs[n] = p;
        }
    }
}

__global__ void k_scatter(const int* __restrict__ src, const int* __restrict__ dst,
                          const int* __restrict__ offs, int* __restrict__ fill,
                          int* __restrict__ esrc, int E_) {
    int i = blockIdx.x * blockDim.x + threadIdx.x;
    if (i < E_) {
        int d = dst[i];
        int pos = offs[d] + atomicAdd(&fill[d], 1);
        esrc[pos] = src[i];
    }
}

// ---------------- fused softmax-stats + gather: wave per node --------------
// agg[n][h][k] = sum_j alpha_jh * X[s_j][k]. alpha held in registers of the
// edge-owning lane, broadcast via dynamic __shfl. Gather is 4-edges-per-
// instruction: lane l loads float4 of row for edge (b + l>>4), covering
// 1 KB per global_load_dwordx4.
__global__ __launch_bounds__(256) void k_sg(
    const int* __restrict__ esrc, const int* __restrict__ offs,
    const float* __restrict__ el, const float* __restrict__ er,
    const float* __restrict__ X, float* __restrict__ agg, int nNodes)
{
    int lane = threadIdx.x & 63, wid = threadIdx.x >> 6;
    int n = blockIdx.x * 4 + wid;
    if (n >= nNodes) return;
    int s0 = offs[n], s1 = offs[n + 1];
    float4* aggr = reinterpret_cast<float4*>(agg + (size_t)n * 256);
    if (s0 == s1) {
        if (lane < 16) {
            float4 z = make_float4(0.f, 0.f, 0.f, 0.f);
            aggr[lane] = z; aggr[16 + lane] = z; aggr[32 + lane] = z; aggr[48 + lane] = z;
        }
        return;
    }
    float4 erv = *reinterpret_cast<const float4*>(er + (size_t)n * 4);
    int d = s1 - s0;

    // ---- stats: chunk 0 cached in registers ----
    int sreg = 0;
    float e0 = -1e30f, e1 = -1e30f, e2 = -1e30f, e3 = -1e30f;
    if (lane < d) {
        sreg = esrc[s0 + lane];
        float4 v = *reinterpret_cast<const float4*>(el + (size_t)sreg * 4);
        e0 = lrelu(v.x + erv.x); e1 = lrelu(v.y + erv.y);
        e2 = lrelu(v.z + erv.z); e3 = lrelu(v.w + erv.w);
    }
    float m0 = e0, m1 = e1, m2 = e2, m3 = e3;
    for (int j = s0 + lane + 64; j < s1; j += 64) {   // rare (deg > 64)
        int s = esrc[j];
        float4 v = *reinterpret_cast<const float4*>(el + (size_t)s * 4);
        m0 = fmaxf(m0, lrelu(v.x + erv.x)); m1 = fmaxf(m1, lrelu(v.y + erv.y));
        m2 = fmaxf(m2, lrelu(v.z + erv.z)); m3 = fmaxf(m3, lrelu(v.w + erv.w));
    }
#pragma unroll
    for (int m = 1; m < 64; m <<= 1) {
        m0 = fmaxf(m0, __shfl_xor(m0, m, 64));
        m1 = fmaxf(m1, __shfl_xor(m1, m, 64));
        m2 = fmaxf(m2, __shfl_xor(m2, m, 64));
        m3 = fmaxf(m3, __shfl_xor(m3, m, 64));
    }
    float x0 = expf(e0 - m0), x1 = expf(e1 - m1), x2 = expf(e2 - m2), x3 = expf(e3 - m3);
    float t0 = x0, t1 = x1, t2 = x2, t3 = x3;
    for (int j = s0 + lane + 64; j < s1; j += 64) {
        int s = esrc[j];
        float4 v = *reinterpret_cast<const float4*>(el + (size_t)s * 4);
        t0 += expf(lrelu(v.x + erv.x) - m0); t1 += expf(lrelu(v.y + erv.y) - m1);
        t2 += expf(lrelu(v.z + erv.z) - m2); t3 += expf(lrelu(v.w + erv.w) - m3);
    }
#pragma unroll
    for (int m = 1; m < 64; m <<= 1) {
        t0 += __shfl_xor(t0, m, 64); t1 += __shfl_xor(t1, m, 64);
        t2 += __shfl_xor(t2, m, 64); t3 += __shfl_xor(t3, m, 64);
    }
    float i0 = 1.f / t0, i1 = 1.f / t1, i2 = 1.f / t2, i3 = 1.f / t3;
    float a0 = x0 * i0, a1 = x1 * i1, a2 = x2 * i2, a3 = x3 * i3;  // alpha (this lane's edge)

    // ---- gather: 4 edges per iteration ----
    int g = lane >> 4, l4 = (lane & 15) * 4;
    float4 A0 = make_float4(0.f, 0.f, 0.f, 0.f), A1 = A0, A2 = A0, A3 = A0;
    int base = s0;
    bool first = true;
    while (base < s1) {
        int cnt = s1 - base; if (cnt > 64) cnt = 64;
        int sj; float w0, w1, w2, w3;
        if (first) { sj = sreg; w0 = a0; w1 = a1; w2 = a2; w3 = a3; }
        else {
            sj = 0; w0 = w1 = w2 = w3 = 0.f;
            if (lane < cnt) {
                sj = esrc[base + lane];
                float4 v = *reinterpret_cast<const float4*>(el + (size_t)sj * 4);
                w0 = expf(lrelu(v.x + erv.x) - m0) * i0;
                w1 = expf(lrelu(v.y + erv.y) - m1) * i1;
                w2 = expf(lrelu(v.z + erv.z) - m2) * i2;
                w3 = expf(lrelu(v.w + erv.w) - m3) * i3;
            }
        }
        for (int b = 0; b < cnt; b += 4) {
            int j = b + g;                       // this 16-lane group's edge
            int s = __shfl(sj, j, 64);
            float q0 = __shfl(w0, j, 64), q1 = __shfl(w1, j, 64);
            float q2 = __shfl(w2, j, 64), q3 = __shfl(w3, j, 64);
            if (j < cnt) {
                float4 xv = *reinterpret_cast<const float4*>(X + (size_t)s * 64 + l4);
                A0.x = fmaf(q0, xv.x, A0.x); A0.y = fmaf(q0, xv.y, A0.y);
                A0.z = fmaf(q0, xv.z, A0.z); A0.w = fmaf(q0, xv.w, A0.w);
                A1.x = fmaf(q1, xv.x, A1.x); A1.y = fmaf(q1, xv.y, A1.y);
                A1.z = fmaf(q1, xv.z, A1.z); A1.w = fmaf(q1, xv.w, A1.w);
                A2.x = fmaf(q2, xv.x, A2.x); A2.y = fmaf(q2, xv.y, A2.y);
                A2.z = fmaf(q2, xv.z, A2.z); A2.w = fmaf(q2, xv.w, A2.w);
                A3.x = fmaf(q3, xv.x, A3.x); A3.y = fmaf(q3, xv.y, A3.y);
                A3.z = fmaf(q3, xv.z, A3.z); A3.w = fmaf(q3, xv.w, A3.w);
            }
        }
        base += 64; first = false;
    }
    // reduce the 4 16-lane groups
#pragma unroll
    for (int mm = 16; mm <= 32; mm <<= 1) {
        A0.x += __shfl_xor(A0.x, mm, 64); A0.y += __shfl_xor(A0.y, mm, 64);
        A0.z += __shfl_xor(A0.z, mm, 64); A0.w += __shfl_xor(A0.w, mm, 64);
        A1.x += __shfl_xor(A1.x, mm, 64); A1.y += __shfl_xor(A1.y, mm, 64);
        A1.z += __shfl_xor(A1.z, mm, 64); A1.w += __shfl_xor(A1.w, mm, 64);
        A2.x += __shfl_xor(A2.x, mm, 64); A2.y += __shfl_xor(A2.y, mm, 64);
        A2.z += __shfl_xor(A2.z, mm, 64); A2.w += __shfl_xor(A2.w, mm, 64);
        A3.x += __shfl_xor(A3.x, mm, 64); A3.y += __shfl_xor(A3.y, mm, 64);
        A3.z += __shfl_xor(A3.z, mm, 64); A3.w += __shfl_xor(A3.w, mm, 64);
    }
    if (lane < 16) {
        aggr[lane] = A0; aggr[16 + lane] = A1; aggr[32 + lane] = A2; aggr[48 + lane] = A3;
    }
}

// ---------------- projection: LDS-staged, 16 nodes per tile ----------------
// + bias, optional tanh, head-mean; optional fused el/er for next layer.
#define PN 16
__global__ __launch_bounds__(256) void k_proj(
    const float* __restrict__ agg, const float* __restrict__ W,
    const float* __restrict__ B, float* __restrict__ out,
    const float* __restrict__ Al, const float* __restrict__ Ar,
    float* __restrict__ el, float* __restrict__ er,
    int nNodes, int nTiles, int do_tanh)
{
    int tid = threadIdx.x, lane = tid & 63, wid = tid >> 6;
    int hb = __builtin_amdgcn_readfirstlane(wid);
    float wcol[64];
#pragma unroll
    for (int k = 0; k < 64; ++k) wcol[k] = W[k * 256 + tid];
    float bv = B[tid];
    float4 av = make_float4(0.f, 0.f, 0.f, 0.f), rv = av;
    if (Al) {
        av = *reinterpret_cast<const float4*>(Al + lane * 4);
        rv = *reinterpret_cast<const float4*>(Ar + lane * 4);
    }
    __shared__ float sA[PN * 256];
    float4* sp = reinterpret_cast<float4*>(sA);

    for (int tile = blockIdx.x; tile < nTiles; tile += gridDim.x) {
        int n0 = tile * PN;
        __syncthreads();  // previous tile's final reads done
        const float4* ap = reinterpret_cast<const float4*>(agg + (size_t)n0 * 256);
        if (n0 + PN <= nNodes) {
#pragma unroll
            for (int i = 0; i < 4; ++i) sp[tid + 256 * i] = ap[tid + 256 * i];
        } else {
#pragma unroll
            for (int i = 0; i < 4; ++i) {
                int idx = tid + 256 * i;
                sp[idx] = (n0 + (idx >> 6) < nNodes) ? ap[idx]
                                                     : make_float4(0.f, 0.f, 0.f, 0.f);
            }
        }
        __syncthreads();
        float v[PN];
#pragma unroll
        for (int ni = 0; ni < PN; ++ni) {
            const float* arow = sA + ni * 256 + hb * 64;
            float c0 = 0.f, c1 = 0.f, c2 = 0.f, c3 = 0.f;
#pragma unroll
            for (int k = 0; k < 64; k += 4) {
                c0 = fmaf(arow[k + 0], wcol[k + 0], c0);
                c1 = fmaf(arow[k + 1], wcol[k + 1], c1);
                c2 = fmaf(arow[k + 2], wcol[k + 2], c2);
                c3 = fmaf(arow[k + 3], wcol[k + 3], c3);
            }
            float vv = (c0 + c1) + (c2 + c3) + bv;
            if (do_tanh) vv = tanhf(vv);
            v[ni] = vv;
        }
        __syncthreads();
#pragma unroll
        for (int ni = 0; ni < PN; ++ni) sA[ni * 256 + tid] = v[ni];
        __syncthreads();
        // head-mean + store (+ fused next-layer el/er)
#pragma unroll
        for (int i = 0; i < 4; ++i) {
            int nl = wid + 4 * i;
            int n = n0 + nl;
            if (n < nNodes) {
                const float* r0 = sA + nl * 256;
                float r = 0.25f * (r0[lane] + r0[64 + lane] + r0[128 + lane] + r0[192 + lane]);
                out[(size_t)n * 64 + lane] = r;
                if (Al) {
                    float p0 = r * av.x, p1 = r * av.y, p2 = r * av.z, p3 = r * av.w;
                    float q0 = r * rv.x, q1 = r * rv.y, q2 = r * rv.z, q3 = r * rv.w;
#pragma unroll
                    for (int mm = 1; mm < 64; mm <<= 1) {
                        p0 += __shfl_xor(p0, mm, 64); p1 += __shfl_xor(p1, mm, 64);
                        p2 += __shfl_xor(p2, mm, 64); p3 += __shfl_xor(p3, mm, 64);
                        q0 += __shfl_xor(q0, mm, 64); q1 += __shfl_xor(q1, mm, 64);
                        q2 += __shfl_xor(q2, mm, 64); q3 += __shfl_xor(q3, mm, 64);
                    }
                    if (lane == 0) {
                        *reinterpret_cast<float4*>(el + (size_t)n * 4) = make_float4(p0, p1, p2, p3);
                        *reinterpret_cast<float4*>(er + (size_t)n * 4) = make_float4(q0, q1, q2, q3);
                    }
                }
            }
        }
    }
}

// ---------------- launch -------------------
extern "C" void kernel_launch(void* const* d_in, const int* in_sizes, int n_in,
                              void* d_out, int out_size, void* d_ws, size_t ws_size,
                              hipStream_t stream) {
    const float* x   = (const float*)d_in[0];
    const int*   src = (const int*)d_in[1];
    const int*   dst = (const int*)d_in[2];
    const float* W1  = (const float*)d_in[3];
    const float* al1 = (const float*)d_in[4];
    const float* ar1 = (const float*)d_in[5];
    const float* b1  = (const float*)d_in[6];
    const float* W2  = (const float*)d_in[7];
    const float* al2 = (const float*)d_in[8];
    const float* ar2 = (const float*)d_in[9];
    const float* b2  = (const float*)d_in[10];
    float* out = (float*)d_out;

    int N_ = in_sizes[0] / 64;
    int E_ = in_sizes[1];

    char* ws = (char*)d_ws;
    size_t off = 0;
    auto alloc = [&](size_t bytes) -> void* {
        void* p = ws + off;
        off = (off + bytes + 255) & ~(size_t)255;
        return p;
    };
    float* agg  = (float*)alloc((size_t)N_ * 256 * 4);
    float* el   = (float*)alloc((size_t)N_ * 4 * 4);
    float* er   = (float*)alloc((size_t)N_ * 4 * 4);
    float* h1   = (float*)alloc((size_t)N_ * 64 * 4);
    int*   cnt  = (int*)alloc((size_t)N_ * 4);
    int*   offs = (int*)alloc((size_t)(N_ + 1) * 4);
    int*   fill = (int*)alloc((size_t)N_ * 4);
    int*   esrc = (int*)alloc((size_t)E_ * 4);
    int*   bsums= (int*)alloc(4096);
    float* A1l  = (float*)alloc(64 * 4 * 4);
    float* A1r  = (float*)alloc(64 * 4 * 4);
    float* A2l  = (float*)alloc(64 * 4 * 4);
    float* A2r  = (float*)alloc(64 * 4 * 4);

    hipMemsetAsync(cnt, 0, (size_t)N_ * 4, stream);
    hipMemsetAsync(fill, 0, (size_t)N_ * 4, stream);

    k_prep<<<1, 256, 0, stream>>>(W1, al1, ar1, A1l, A1r);
    k_prep<<<1, 256, 0, stream>>>(W2, al2, ar2, A2l, A2r);

    int eb = (E_ + 255) / 256;
    k_hist<<<eb, 256, 0, stream>>>(dst, cnt, E_);
    int nchunks = (N_ + SC_CHUNK - 1) / SC_CHUNK;
    k_chunk_sums<<<nchunks, 256, 0, stream>>>(cnt, bsums, N_);
    k_scan_mid<<<1, 64, 0, stream>>>(bsums, nchunks);
    k_scan_write<<<nchunks, 256, 0, stream>>>(cnt, bsums, offs, N_);
    k_scatter<<<eb, 256, 0, stream>>>(src, dst, offs, fill, esrc, E_);

    int nb4 = (N_ + 3) / 4;
    int nTiles = (N_ + PN - 1) / PN;
    int pgrid = nTiles < 2560 ? nTiles : 2560;
    // layer 1 (k_proj also emits layer-2 el/er)
    k_elr<<<nb4, 256, 0, stream>>>(x, A1l, A1r, el, er, N_);
    k_sg<<<nb4, 256, 0, stream>>>(esrc, offs, el, er, x, agg, N_);
    k_proj<<<pgrid, 256, 0, stream>>>(agg, W1, b1, h1, A2l, A2r, el, er, N_, nTiles, 1);
    // layer 2
    k_sg<<<nb4, 256, 0, stream>>>(esrc, offs, el, er, h1, agg, N_);
    k_proj<<<pgrid, 256, 0, stream>>>(agg, W2, b2, out, nullptr, nullptr, nullptr, nullptr, N_, nTiles, 0);
}

// Round 5
// 604.315 us; speedup vs baseline: 1.2910x; 1.1193x over previous
//
#include <hip/hip_runtime.h>

typedef _Float16 f16x8 __attribute__((ext_vector_type(8)));
typedef _Float16 f16x4 __attribute__((ext_vector_type(4)));
typedef float f32x4 __attribute__((ext_vector_type(4)));

__device__ __forceinline__ float lrelu(float v) { return v >= 0.f ? v : 0.2f * v; }

// ---------------- prep: A_l[k][h] = sum_f W[k][h*64+f]*al[h][f] ------------
__global__ __launch_bounds__(256) void k_prep(
    const float* __restrict__ W, const float* __restrict__ al,
    const float* __restrict__ ar, float* __restrict__ Al, float* __restrict__ Ar)
{
    int t = threadIdx.x;
    int k = t >> 2, h = t & 3;
    float sl = 0.f, sr = 0.f;
#pragma unroll 8
    for (int f = 0; f < 64; ++f) {
        float wv = W[k * 256 + h * 64 + f];
        sl = fmaf(wv, al[h * 64 + f], sl);
        sr = fmaf(wv, ar[h * 64 + f], sr);
    }
    Al[k * 4 + h] = sl;
    Ar[k * 4 + h] = sr;
}

// ---------------- Wt[col][k] = (fp16) W[k][col] ----------------------------
__global__ __launch_bounds__(256) void k_wt(const float* __restrict__ W,
                                            _Float16* __restrict__ Wt) {
    int col = threadIdx.x;
#pragma unroll 8
    for (int k = 0; k < 64; ++k)
        Wt[col * 64 + k] = (_Float16)W[k * 256 + col];
}

// ---------------- el/er = X @ [Al|Ar] : wave per node ----------------------
__global__ __launch_bounds__(256) void k_elr(
    const float* __restrict__ X, const float* __restrict__ Al,
    const float* __restrict__ Ar, float* __restrict__ el, float* __restrict__ er,
    int nNodes)
{
    int lane = threadIdx.x & 63, wid = threadIdx.x >> 6;
    int n = blockIdx.x * 4 + wid;
    if (n >= nNodes) return;
    float xv = X[(size_t)n * 64 + lane];
    float4 a = *reinterpret_cast<const float4*>(Al + lane * 4);
    float4 r = *reinterpret_cast<const float4*>(Ar + lane * 4);
    float p0 = xv * a.x, p1 = xv * a.y, p2 = xv * a.z, p3 = xv * a.w;
    float q0 = xv * r.x, q1 = xv * r.y, q2 = xv * r.z, q3 = xv * r.w;
#pragma unroll
    for (int m = 1; m < 64; m <<= 1) {
        p0 += __shfl_xor(p0, m, 64); p1 += __shfl_xor(p1, m, 64);
        p2 += __shfl_xor(p2, m, 64); p3 += __shfl_xor(p3, m, 64);
        q0 += __shfl_xor(q0, m, 64); q1 += __shfl_xor(q1, m, 64);
        q2 += __shfl_xor(q2, m, 64); q3 += __shfl_xor(q3, m, 64);
    }
    if (lane == 0) {
        *reinterpret_cast<float4*>(el + (size_t)n * 4) = make_float4(p0, p1, p2, p3);
        *reinterpret_cast<float4*>(er + (size_t)n * 4) = make_float4(q0, q1, q2, q3);
    }
}

// ---------------- CSR build -------------------
__global__ void k_hist(const int* __restrict__ dst, int* __restrict__ cnt, int E_) {
    int i = blockIdx.x * blockDim.x + threadIdx.x;
    if (i < E_) atomicAdd(&cnt[dst[i]], 1);
}

#define SC_VPT 8
#define SC_CHUNK 2048  // 256 threads * 8

__global__ __launch_bounds__(256) void k_chunk_sums(const int* __restrict__ cnt,
                                                    int* __restrict__ bsums, int n) {
    int tid = threadIdx.x;
    int base = blockIdx.x * SC_CHUNK + tid * SC_VPT;
    int s = 0;
#pragma unroll
    for (int i = 0; i < SC_VPT; ++i) { int idx = base + i; if (idx < n) s += cnt[idx]; }
    int lane = tid & 63, wid = tid >> 6;
#pragma unroll
    for (int m = 1; m < 64; m <<= 1) s += __shfl_xor(s, m, 64);
    __shared__ int sh[4];
    if (lane == 0) sh[wid] = s;
    __syncthreads();
    if (tid == 0) bsums[blockIdx.x] = sh[0] + sh[1] + sh[2] + sh[3];
}

__global__ void k_scan_mid(int* bsums, int nb) {
    if (threadIdx.x == 0 && blockIdx.x == 0) {
        int acc = 0;
        for (int i = 0; i < nb; ++i) { int v = bsums[i]; bsums[i] = acc; acc += v; }
    }
}

__global__ __launch_bounds__(256) void k_scan_write(const int* __restrict__ cnt,
                                                    const int* __restrict__ bsums,
                                                    int* __restrict__ offs, int n) {
    int tid = threadIdx.x;
    int base = blockIdx.x * SC_CHUNK + tid * SC_VPT;
    int v[SC_VPT]; int s = 0;
#pragma unroll
    for (int i = 0; i < SC_VPT; ++i) { int idx = base + i; v[i] = (idx < n) ? cnt[idx] : 0; s += v[i]; }
    int lane = tid & 63, wid = tid >> 6;
    int sc = s;
#pragma unroll
    for (int d = 1; d < 64; d <<= 1) { int t = __shfl_up(sc, d, 64); if (lane >= d) sc += t; }
    __shared__ int wsum[4];
    if (lane == 63) wsum[wid] = sc;
    __syncthreads();
    int wbase = 0;
    for (int i = 0; i < wid; ++i) wbase += wsum[i];
    int p = bsums[blockIdx.x] + wbase + (sc - s);
#pragma unroll
    for (int i = 0; i < SC_VPT; ++i) {
        int idx = base + i;
        if (idx < n) {
            offs[idx] = p; p += v[i];
            if (idx == n - 1) offs[n] = p;
        }
    }
}

__global__ void k_scatter(const int* __restrict__ src, const int* __restrict__ dst,
                          const int* __restrict__ offs, int* __restrict__ fill,
                          int* __restrict__ esrc, int E_) {
    int i = blockIdx.x * blockDim.x + threadIdx.x;
    if (i < E_) {
        int d = dst[i];
        int pos = offs[d] + atomicAdd(&fill[d], 1);
        esrc[pos] = src[i];
    }
}

// ---------------- fused softmax-stats + gather: wave per node --------------
// agg (fp16) [n][h*64+k] = sum_j alpha_jh * X[s_j][k].
__global__ __launch_bounds__(256) void k_sg(
    const int* __restrict__ esrc, const int* __restrict__ offs,
    const float* __restrict__ el, const float* __restrict__ er,
    const float* __restrict__ X, _Float16* __restrict__ agg, int nNodes)
{
    int lane = threadIdx.x & 63, wid = threadIdx.x >> 6;
    int n = blockIdx.x * 4 + wid;
    if (n >= nNodes) return;
    int s0 = offs[n], s1 = offs[n + 1];
    _Float16* aggr = agg + (size_t)n * 256;
    if (s0 == s1) {
        if (lane < 16) {
            f16x4 z = {0.f16, 0.f16, 0.f16, 0.f16};
            *reinterpret_cast<f16x4*>(aggr + lane * 4)       = z;
            *reinterpret_cast<f16x4*>(aggr + 64 + lane * 4)  = z;
            *reinterpret_cast<f16x4*>(aggr + 128 + lane * 4) = z;
            *reinterpret_cast<f16x4*>(aggr + 192 + lane * 4) = z;
        }
        return;
    }
    float4 erv = *reinterpret_cast<const float4*>(er + (size_t)n * 4);
    int d = s1 - s0;

    // ---- stats: chunk 0 cached in registers ----
    int sreg = 0;
    float e0 = -1e30f, e1 = -1e30f, e2 = -1e30f, e3 = -1e30f;
    if (lane < d) {
        sreg = esrc[s0 + lane];
        float4 v = *reinterpret_cast<const float4*>(el + (size_t)sreg * 4);
        e0 = lrelu(v.x + erv.x); e1 = lrelu(v.y + erv.y);
        e2 = lrelu(v.z + erv.z); e3 = lrelu(v.w + erv.w);
    }
    float m0 = e0, m1 = e1, m2 = e2, m3 = e3;
    for (int j = s0 + lane + 64; j < s1; j += 64) {
        int s = esrc[j];
        float4 v = *reinterpret_cast<const float4*>(el + (size_t)s * 4);
        m0 = fmaxf(m0, lrelu(v.x + erv.x)); m1 = fmaxf(m1, lrelu(v.y + erv.y));
        m2 = fmaxf(m2, lrelu(v.z + erv.z)); m3 = fmaxf(m3, lrelu(v.w + erv.w));
    }
#pragma unroll
    for (int m = 1; m < 64; m <<= 1) {
        m0 = fmaxf(m0, __shfl_xor(m0, m, 64));
        m1 = fmaxf(m1, __shfl_xor(m1, m, 64));
        m2 = fmaxf(m2, __shfl_xor(m2, m, 64));
        m3 = fmaxf(m3, __shfl_xor(m3, m, 64));
    }
    float x0 = expf(e0 - m0), x1 = expf(e1 - m1), x2 = expf(e2 - m2), x3 = expf(e3 - m3);
    float t0 = x0, t1 = x1, t2 = x2, t3 = x3;
    for (int j = s0 + lane + 64; j < s1; j += 64) {
        int s = esrc[j];
        float4 v = *reinterpret_cast<const float4*>(el + (size_t)s * 4);
        t0 += expf(lrelu(v.x + erv.x) - m0); t1 += expf(lrelu(v.y + erv.y) - m1);
        t2 += expf(lrelu(v.z + erv.z) - m2); t3 += expf(lrelu(v.w + erv.w) - m3);
    }
#pragma unroll
    for (int m = 1; m < 64; m <<= 1) {
        t0 += __shfl_xor(t0, m, 64); t1 += __shfl_xor(t1, m, 64);
        t2 += __shfl_xor(t2, m, 64); t3 += __shfl_xor(t3, m, 64);
    }
    float i0 = 1.f / t0, i1 = 1.f / t1, i2 = 1.f / t2, i3 = 1.f / t3;
    float a0 = x0 * i0, a1 = x1 * i1, a2 = x2 * i2, a3 = x3 * i3;

    // ---- gather: 4 edges per iteration (1 KB per dwordx4 wave-instr) ----
    int g = lane >> 4, l4 = (lane & 15) * 4;
    float4 A0 = make_float4(0.f, 0.f, 0.f, 0.f), A1 = A0, A2 = A0, A3 = A0;
    int base = s0;
    bool first = true;
    while (base < s1) {
        int cnt = s1 - base; if (cnt > 64) cnt = 64;
        int sj; float w0, w1, w2, w3;
        if (first) { sj = sreg; w0 = a0; w1 = a1; w2 = a2; w3 = a3; }
        else {
            sj = 0; w0 = w1 = w2 = w3 = 0.f;
            if (lane < cnt) {
                sj = esrc[base + lane];
                float4 v = *reinterpret_cast<const float4*>(el + (size_t)sj * 4);
                w0 = expf(lrelu(v.x + erv.x) - m0) * i0;
                w1 = expf(lrelu(v.y + erv.y) - m1) * i1;
                w2 = expf(lrelu(v.z + erv.z) - m2) * i2;
                w3 = expf(lrelu(v.w + erv.w) - m3) * i3;
            }
        }
        for (int b = 0; b < cnt; b += 4) {
            int j = b + g;
            int s = __shfl(sj, j, 64);
            float q0 = __shfl(w0, j, 64), q1 = __shfl(w1, j, 64);
            float q2 = __shfl(w2, j, 64), q3 = __shfl(w3, j, 64);
            if (j < cnt) {
                float4 xv = *reinterpret_cast<const float4*>(X + (size_t)s * 64 + l4);
                A0.x = fmaf(q0, xv.x, A0.x); A0.y = fmaf(q0, xv.y, A0.y);
                A0.z = fmaf(q0, xv.z, A0.z); A0.w = fmaf(q0, xv.w, A0.w);
                A1.x = fmaf(q1, xv.x, A1.x); A1.y = fmaf(q1, xv.y, A1.y);
                A1.z = fmaf(q1, xv.z, A1.z); A1.w = fmaf(q1, xv.w, A1.w);
                A2.x = fmaf(q2, xv.x, A2.x); A2.y = fmaf(q2, xv.y, A2.y);
                A2.z = fmaf(q2, xv.z, A2.z); A2.w = fmaf(q2, xv.w, A2.w);
                A3.x = fmaf(q3, xv.x, A3.x); A3.y = fmaf(q3, xv.y, A3.y);
                A3.z = fmaf(q3, xv.z, A3.z); A3.w = fmaf(q3, xv.w, A3.w);
            }
        }
        base += 64; first = false;
    }
#pragma unroll
    for (int mm = 16; mm <= 32; mm <<= 1) {
        A0.x += __shfl_xor(A0.x, mm, 64); A0.y += __shfl_xor(A0.y, mm, 64);
        A0.z += __shfl_xor(A0.z, mm, 64); A0.w += __shfl_xor(A0.w, mm, 64);
        A1.x += __shfl_xor(A1.x, mm, 64); A1.y += __shfl_xor(A1.y, mm, 64);
        A1.z += __shfl_xor(A1.z, mm, 64); A1.w += __shfl_xor(A1.w, mm, 64);
        A2.x += __shfl_xor(A2.x, mm, 64); A2.y += __shfl_xor(A2.y, mm, 64);
        A2.z += __shfl_xor(A2.z, mm, 64); A2.w += __shfl_xor(A2.w, mm, 64);
        A3.x += __shfl_xor(A3.x, mm, 64); A3.y += __shfl_xor(A3.y, mm, 64);
        A3.z += __shfl_xor(A3.z, mm, 64); A3.w += __shfl_xor(A3.w, mm, 64);
    }
    if (lane < 16) {
        f16x4 h0 = {(_Float16)A0.x, (_Float16)A0.y, (_Float16)A0.z, (_Float16)A0.w};
        f16x4 h1v = {(_Float16)A1.x, (_Float16)A1.y, (_Float16)A1.z, (_Float16)A1.w};
        f16x4 h2 = {(_Float16)A2.x, (_Float16)A2.y, (_Float16)A2.z, (_Float16)A2.w};
        f16x4 h3 = {(_Float16)A3.x, (_Float16)A3.y, (_Float16)A3.z, (_Float16)A3.w};
        *reinterpret_cast<f16x4*>(aggr + lane * 4)       = h0;
        *reinterpret_cast<f16x4*>(aggr + 64 + lane * 4)  = h1v;
        *reinterpret_cast<f16x4*>(aggr + 128 + lane * 4) = h2;
        *reinterpret_cast<f16x4*>(aggr + 192 + lane * 4) = h3;
    }
}

// ---------------- MFMA projection --------------------------------------
// 16-node tiles. Wave w owns f-coltile [w*16, w*16+16); computes all 4 heads,
// fuses bias + optional tanh + head-mean. B-frags (Wt) persistent in VGPRs.
// A-frag: a[m=lane&15][k=quad*8+j]; D: col=lane&15, row=quad*4+reg.
__global__ __launch_bounds__(256) void k_projm(
    const _Float16* __restrict__ agg, const _Float16* __restrict__ Wt,
    const float* __restrict__ B, float* __restrict__ out,
    int nTiles, int do_tanh)
{
    int tid = threadIdx.x, lane = tid & 63, wf = tid >> 6;
    int col = lane & 15, quad = lane >> 4;
    int f0 = wf * 16;

    f16x8 bfrag[4][2];
    float bias[4];
#pragma unroll
    for (int h = 0; h < 4; ++h) {
#pragma unroll
        for (int ks = 0; ks < 2; ++ks)
            bfrag[h][ks] = *reinterpret_cast<const f16x8*>(
                Wt + (h * 64 + f0 + col) * 64 + ks * 32 + quad * 8);
        bias[h] = B[h * 64 + f0 + col];
    }

    for (int tile = blockIdx.x; tile < nTiles; tile += gridDim.x) {
        int n0 = tile * 16;
        const _Float16* ap = agg + (size_t)n0 * 256 + (lane & 15) * 256 + quad * 8;
        f32x4 acc = {0.f, 0.f, 0.f, 0.f};
#pragma unroll
        for (int h = 0; h < 4; ++h) {
            f16x8 a0 = *reinterpret_cast<const f16x8*>(ap + h * 64);
            f16x8 a1 = *reinterpret_cast<const f16x8*>(ap + h * 64 + 32);
            f32x4 dd = {0.f, 0.f, 0.f, 0.f};
            dd = __builtin_amdgcn_mfma_f32_16x16x32_f16(a0, bfrag[h][0], dd, 0, 0, 0);
            dd = __builtin_amdgcn_mfma_f32_16x16x32_f16(a1, bfrag[h][1], dd, 0, 0, 0);
            if (do_tanh) {
#pragma unroll
                for (int r = 0; r < 4; ++r) acc[r] += tanhf(dd[r] + bias[h]);
            } else {
#pragma unroll
                for (int r = 0; r < 4; ++r) acc[r] += dd[r] + bias[h];
            }
        }
#pragma unroll
        for (int r = 0; r < 4; ++r)
            out[(size_t)(n0 + quad * 4 + r) * 64 + f0 + col] = 0.25f * acc[r];
    }
}

// ---------------- launch -------------------
extern "C" void kernel_launch(void* const* d_in, const int* in_sizes, int n_in,
                              void* d_out, int out_size, void* d_ws, size_t ws_size,
                              hipStream_t stream) {
    const float* x   = (const float*)d_in[0];
    const int*   src = (const int*)d_in[1];
    const int*   dst = (const int*)d_in[2];
    const float* W1  = (const float*)d_in[3];
    const float* al1 = (const float*)d_in[4];
    const float* ar1 = (const float*)d_in[5];
    const float* b1  = (const float*)d_in[6];
    const float* W2  = (const float*)d_in[7];
    const float* al2 = (const float*)d_in[8];
    const float* ar2 = (const float*)d_in[9];
    const float* b2  = (const float*)d_in[10];
    float* out = (float*)d_out;

    int N_ = in_sizes[0] / 64;
    int E_ = in_sizes[1];

    char* ws = (char*)d_ws;
    size_t off = 0;
    auto alloc = [&](size_t bytes) -> void* {
        void* p = ws + off;
        off = (off + bytes + 255) & ~(size_t)255;
        return p;
    };
    _Float16* agg = (_Float16*)alloc(((size_t)N_ + 16) * 256 * 2);
    float* el   = (float*)alloc((size_t)N_ * 4 * 4);
    float* er   = (float*)alloc((size_t)N_ * 4 * 4);
    float* h1   = (float*)alloc((size_t)N_ * 64 * 4);
    int*   cnt  = (int*)alloc((size_t)N_ * 4);
    int*   offs = (int*)alloc((size_t)(N_ + 1) * 4);
    int*   fill = (int*)alloc((size_t)N_ * 4);
    int*   esrc = (int*)alloc((size_t)E_ * 4);
    int*   bsums= (int*)alloc(4096);
    float* A1l  = (float*)alloc(64 * 4 * 4);
    float* A1r  = (float*)alloc(64 * 4 * 4);
    float* A2l  = (float*)alloc(64 * 4 * 4);
    float* A2r  = (float*)alloc(64 * 4 * 4);
    _Float16* Wt1 = (_Float16*)alloc(256 * 64 * 2);
    _Float16* Wt2 = (_Float16*)alloc(256 * 64 * 2);

    hipMemsetAsync(cnt, 0, (size_t)N_ * 4, stream);
    hipMemsetAsync(fill, 0, (size_t)N_ * 4, stream);

    k_prep<<<1, 256, 0, stream>>>(W1, al1, ar1, A1l, A1r);
    k_prep<<<1, 256, 0, stream>>>(W2, al2, ar2, A2l, A2r);
    k_wt<<<1, 256, 0, stream>>>(W1, Wt1);
    k_wt<<<1, 256, 0, stream>>>(W2, Wt2);

    int eb = (E_ + 255) / 256;
    k_hist<<<eb, 256, 0, stream>>>(dst, cnt, E_);
    int nchunks = (N_ + SC_CHUNK - 1) / SC_CHUNK;
    k_chunk_sums<<<nchunks, 256, 0, stream>>>(cnt, bsums, N_);
    k_scan_mid<<<1, 64, 0, stream>>>(bsums, nchunks);
    k_scan_write<<<nchunks, 256, 0, stream>>>(cnt, bsums, offs, N_);
    k_scatter<<<eb, 256, 0, stream>>>(src, dst, offs, fill, esrc, E_);

    int nb4 = (N_ + 3) / 4;
    int nTiles = (N_ + 15) / 16;   // N=100000 -> 6250 exact
    int pgrid = nTiles < 2560 ? nTiles : 2560;
    // layer 1
    k_elr<<<nb4, 256, 0, stream>>>(x, A1l, A1r, el, er, N_);
    k_sg<<<nb4, 256, 0, stream>>>(esrc, offs, el, er, x, agg, N_);
    k_projm<<<pgrid, 256, 0, stream>>>(agg, Wt1, b1, h1, nTiles, 1);
    // layer 2
    k_elr<<<nb4, 256, 0, stream>>>(h1, A2l, A2r, el, er, N_);
    k_sg<<<nb4, 256, 0, stream>>>(esrc, offs, el, er, h1, agg, N_);
    k_projm<<<pgrid, 256, 0, stream>>>(agg, Wt2, b2, out, nTiles, 0);
}